// Round 1
// baseline (359.575 us; speedup 1.0000x reference)
//
#include <hip/hip_runtime.h>

#define B_ 2048
#define T_ 256
#define F_ 64
#define EMB_ 16
#define UNITS_ 32
#define CAT_ 48

__device__ __forceinline__ float rlane(float v, int l) {
    return __int_as_float(__builtin_amdgcn_readlane(__float_as_int(v), l));
}
__device__ __forceinline__ float fast_sigmoid(float x) {
    // 1/(1+2^(-x*log2e))
    return __builtin_amdgcn_rcpf(1.0f + __builtin_amdgcn_exp2f(-1.44269504f * x));
}
__device__ __forceinline__ float fast_tanh(float x) {
    // 2*sigmoid(2x) - 1
    return 2.0f * __builtin_amdgcn_rcpf(1.0f + __builtin_amdgcn_exp2f(-2.88539008f * x)) - 1.0f;
}

// One wave (64 lanes) per batch row. 2 waves per 128-thread block.
// lane ell owns gate columns ell and ell+64 of W_gates=[Wf|Wi|Wc|Wo] (48x128).
// h[u] lives in lane u (u<32). z broadcast via v_readlane.
__global__ __launch_bounds__(128) void lstm_fused(
    const float* __restrict__ x,
    const float* __restrict__ Wemb, const float* __restrict__ bemb,
    const float* __restrict__ Wf, const float* __restrict__ bfv,
    const float* __restrict__ Wi, const float* __restrict__ biv,
    const float* __restrict__ Wc, const float* __restrict__ bcv,
    const float* __restrict__ Wo, const float* __restrict__ bov,
    const float* __restrict__ Wout, const float* __restrict__ bout,
    float* __restrict__ out)
{
    __shared__ float sWemb[F_ * EMB_];   // 4 KB
    __shared__ float sBemb[EMB_];
    __shared__ float sE[2][T_ * EMB_];   // 2 waves * 16 KB fp32 embeddings

    const int tid  = threadIdx.x;
    const int w    = tid >> 6;
    const int lane = tid & 63;
    const int row  = blockIdx.x * 2 + w;

    // ---- stage W_emb / b_emb into LDS ----
    for (int i = tid; i < F_ * EMB_; i += 128) sWemb[i] = Wemb[i];
    if (tid < EMB_) sBemb[tid] = bemb[tid];
    __syncthreads();

    // ---- per-lane gate weights (96 VGPRs) ----
    const int  cu = lane & 31;
    const bool lo = (lane < 32);
    const float* W0 = lo ? Wf : Wi;   // column  lane    : f (lo) / i (hi)
    const float* W1 = lo ? Wc : Wo;   // column  lane+64 : c (lo) / o (hi)
    float wg0[CAT_], wg1[CAT_];
    #pragma unroll
    for (int k = 0; k < CAT_; ++k) {
        wg0[k] = W0[k * UNITS_ + cu];
        wg1[k] = W1[k * UNITS_ + cu];
    }
    const float b0v = lo ? bfv[cu] : biv[cu];
    const float b1v = lo ? bcv[cu] : bov[cu];

    // ---- embedding phase: this wave's row, all T, into private LDS slab ----
    const float* xr = x + (size_t)row * (T_ * F_);
    float* eL = &sE[w][0];
    #pragma unroll 1
    for (int to = 0; to < 4; ++to) {
        const int t = to * 64 + lane;
        const float4* xv = (const float4*)(xr + t * F_);
        float acc[EMB_];
        #pragma unroll
        for (int m = 0; m < EMB_; ++m) acc[m] = sBemb[m];
        #pragma unroll
        for (int fi = 0; fi < 16; ++fi) {
            float4 v = xv[fi];
            #pragma unroll
            for (int m = 0; m < EMB_; ++m) {
                acc[m] = fmaf(v.x, sWemb[(4 * fi + 0) * EMB_ + m], acc[m]);
                acc[m] = fmaf(v.y, sWemb[(4 * fi + 1) * EMB_ + m], acc[m]);
                acc[m] = fmaf(v.z, sWemb[(4 * fi + 2) * EMB_ + m], acc[m]);
                acc[m] = fmaf(v.w, sWemb[(4 * fi + 3) * EMB_ + m], acc[m]);
            }
        }
        #pragma unroll
        for (int m = 0; m < EMB_; ++m) eL[t * EMB_ + m] = fast_sigmoid(acc[m]);
    }
    // sE region is wave-private; within-wave LDS ordering is handled by waitcnt,
    // no barrier needed before the recurrence.

    // ---- LSTM recurrence ----
    float h = 0.0f, c = 0.0f;
    #pragma unroll 1
    for (int t = 0; t < T_; ++t) {
        const float ev = eL[t * EMB_ + (lane & 15)];   // lane m holds e[t][m&15]
        float g0a = b0v, g0b = 0.0f, g1a = b1v, g1b = 0.0f;
        #pragma unroll
        for (int k = 0; k < 32; k += 2) {            // z[k] = h[k]
            float z0 = rlane(h, k);
            float z1 = rlane(h, k + 1);
            g0a = fmaf(z0, wg0[k],     g0a);
            g1a = fmaf(z0, wg1[k],     g1a);
            g0b = fmaf(z1, wg0[k + 1], g0b);
            g1b = fmaf(z1, wg1[k + 1], g1b);
        }
        #pragma unroll
        for (int k = 0; k < 16; k += 2) {            // z[32+k] = e[t][k]
            float z0 = rlane(ev, k);
            float z1 = rlane(ev, k + 1);
            g0a = fmaf(z0, wg0[32 + k], g0a);
            g1a = fmaf(z0, wg1[32 + k], g1a);
            g0b = fmaf(z1, wg0[33 + k], g0b);
            g1b = fmaf(z1, wg1[33 + k], g1b);
        }
        const float g0 = g0a + g0b;
        const float g1 = g1a + g1b;

        // a0: sigmoid for both halves (f-gate lo / i-gate hi)
        const float a0 = fast_sigmoid(g0);
        // a1: tanh (lo: candidate) or sigmoid (hi: output gate), branchless
        const float s_in = lo ? (g1 + g1) : g1;
        const float s1   = __builtin_amdgcn_rcpf(1.0f + __builtin_amdgcn_exp2f(-1.44269504f * s_in));
        const float a1   = lo ? (s1 + s1 - 1.0f) : s1;

        const float i_v = __shfl_xor(a0, 32, 64);    // sigmoid(g_i) into lanes<32
        const float o_v = __shfl_xor(a1, 32, 64);    // sigmoid(g_o) into lanes<32

        // lanes<32 hold the real state; hi lanes compute bounded garbage (unread)
        c = fmaf(a0, c, i_v * a1);   // f*c + i*ch
        h = o_v * fast_tanh(c);      // o*tanh(c)
    }

    // ---- output projection: sum over 32 units ----
    float p = lo ? h * Wout[cu] : 0.0f;
    p += __shfl_xor(p, 16, 64);
    p += __shfl_xor(p, 8, 64);
    p += __shfl_xor(p, 4, 64);
    p += __shfl_xor(p, 2, 64);
    p += __shfl_xor(p, 1, 64);
    if (lane == 0) out[row] = fast_sigmoid(p + bout[0]);
}

extern "C" void kernel_launch(void* const* d_in, const int* in_sizes, int n_in,
                              void* d_out, int out_size, void* d_ws, size_t ws_size,
                              hipStream_t stream) {
    const float* x    = (const float*)d_in[0];
    const float* Wemb = (const float*)d_in[1];
    const float* bemb = (const float*)d_in[2];
    const float* Wf   = (const float*)d_in[3];
    const float* bfv  = (const float*)d_in[4];
    const float* Wi   = (const float*)d_in[5];
    const float* biv  = (const float*)d_in[6];
    const float* Wc   = (const float*)d_in[7];
    const float* bcv  = (const float*)d_in[8];
    const float* Wo   = (const float*)d_in[9];
    const float* bov  = (const float*)d_in[10];
    const float* Wout = (const float*)d_in[11];
    const float* bout = (const float*)d_in[12];
    float* out = (float*)d_out;

    dim3 grid(B_ / 2), block(128);
    hipLaunchKernelGGL(lstm_fused, grid, block, 0, stream,
                       x, Wemb, bemb, Wf, bfv, Wi, biv, Wc, bcv, Wo, bov,
                       Wout, bout, out);
}

// Round 2
// 187.486 us; speedup vs baseline: 1.9179x; 1.9179x over previous
//
#include <hip/hip_runtime.h>

#define B_ 2048
#define T_ 256
#define F_ 64
#define EMB_ 16
#define UNITS_ 32

typedef __attribute__((ext_vector_type(8))) short bf16x8;
typedef __attribute__((ext_vector_type(4))) float f32x4;

__device__ __forceinline__ float fast_sigmoid(float x) {
    return __builtin_amdgcn_rcpf(1.0f + __builtin_amdgcn_exp2f(-1.44269504f * x));
}
__device__ __forceinline__ float fast_tanh(float x) {
    return 2.0f * __builtin_amdgcn_rcpf(1.0f + __builtin_amdgcn_exp2f(-2.88539008f * x)) - 1.0f;
}
__device__ __forceinline__ unsigned short f2bf(float f) {  // RNE float->bf16
    unsigned u = __float_as_uint(f);
    unsigned r = (u + 0x7FFFu + ((u >> 16) & 1u)) >> 16;
    return (unsigned short)r;
}

// ---------------- Kernel 1: embedding  e = sigmoid(x @ Wemb + bemb) ----------
// Writes bf16 e to workspace in the recurrence's B-fragment order:
// e_ws[bt][t][b&15][emb], bt = b>>4.   (16 bf16 = 32 B per (b,t))
__global__ __launch_bounds__(256) void embed_kernel(
    const float* __restrict__ x, const float* __restrict__ Wemb,
    const float* __restrict__ bemb, unsigned short* __restrict__ e_ws)
{
    __shared__ float sW[F_ * EMB_];
    __shared__ float sB[EMB_];
    const int b = blockIdx.x, t = threadIdx.x;
    for (int i = t; i < F_ * EMB_; i += 256) sW[i] = Wemb[i];
    if (t < EMB_) sB[t] = bemb[t];
    __syncthreads();

    const float4* xv = (const float4*)(x + ((size_t)b * T_ + t) * F_);
    float acc[EMB_];
    #pragma unroll
    for (int m = 0; m < EMB_; ++m) acc[m] = sB[m];
    #pragma unroll
    for (int fi = 0; fi < 16; ++fi) {
        float4 v = xv[fi];
        #pragma unroll
        for (int m = 0; m < EMB_; ++m) {
            acc[m] = fmaf(v.x, sW[(4 * fi + 0) * EMB_ + m], acc[m]);
            acc[m] = fmaf(v.y, sW[(4 * fi + 1) * EMB_ + m], acc[m]);
            acc[m] = fmaf(v.z, sW[(4 * fi + 2) * EMB_ + m], acc[m]);
            acc[m] = fmaf(v.w, sW[(4 * fi + 3) * EMB_ + m], acc[m]);
        }
    }
    unsigned w[8];
    #pragma unroll
    for (int m = 0; m < 8; ++m) {
        unsigned lo = f2bf(fast_sigmoid(acc[2 * m]));
        unsigned hi = f2bf(fast_sigmoid(acc[2 * m + 1]));
        w[m] = lo | (hi << 16);
    }
    size_t off = (((size_t)(b >> 4) * T_ + t) * 16 + (b & 15)) * 16;  // bf16 elems
    uint4* p = (uint4*)(e_ws + off);
    p[0] = make_uint4(w[0], w[1], w[2], w[3]);
    p[1] = make_uint4(w[4], w[5], w[6], w[7]);
}

// ---------------- Kernel 2: LSTM recurrence via MFMA -------------------------
// One WG (2 waves, 128 thr) per 16-row batch tile. G[128,16] = Wg^T z + b via
// mfma_f32_16x16x32_bf16: A = weight frags (M=16 tile of gate rows), B = z.
// Wave uh owns unit half [16uh,16uh+16): its 4 M-tiles are the 4 gates for
// those units, so each lane's C regs = 4 cells (batch=lane&15,
// unit=16uh+4*(lane>>4)+r), and its h outputs are exactly its own B-slots.
__global__ __launch_bounds__(128) void lstm_rec(
    const float* __restrict__ Wf, const float* __restrict__ bfv,
    const float* __restrict__ Wi, const float* __restrict__ biv,
    const float* __restrict__ Wc, const float* __restrict__ bcv,
    const float* __restrict__ Wo, const float* __restrict__ bov,
    const float* __restrict__ Wout, const float* __restrict__ bout,
    const unsigned short* __restrict__ e_ws, float* __restrict__ out)
{
    __shared__ ushort4 xch[2][2][64];   // [parity][wave][lane]
    __shared__ float pred[2][16];

    const int tid = threadIdx.x;
    const int uh = tid >> 6;          // unit-half wave
    const int lane = tid & 63;
    const int g = lane >> 4, m15 = lane & 15;
    const int bt = blockIdx.x;

    const float* Wg[4] = {Wf, Wi, Wc, Wo};
    const float* bg[4] = {bfv, biv, bcv, bov};

    // ---- static A fragments + bias (gauge: slot(g,j) <-> k = 4g+j | 16+4g+j-4)
    bf16x8 Ah[4], Ae[4];
    f32x4 bias[4];
    #pragma unroll
    for (int gi = 0; gi < 4; ++gi) {
        #pragma unroll
        for (int j = 0; j < 4; ++j) {
            Ah[gi][j]     = (short)f2bf(Wg[gi][(4 * g + j) * UNITS_ + 16 * uh + m15]);
            Ah[gi][j + 4] = (short)f2bf(Wg[gi][(16 + 4 * g + j) * UNITS_ + 16 * uh + m15]);
            Ae[gi][j]     = (short)f2bf(Wg[gi][(32 + 4 * g + j) * UNITS_ + 16 * uh + m15]);
            Ae[gi][j + 4] = 0;
        }
        #pragma unroll
        for (int r = 0; r < 4; ++r) bias[gi][r] = bg[gi][16 * uh + 4 * g + r];
    }

    const unsigned short* eb = e_ws + (size_t)bt * T_ * 256 + m15 * 16 + 4 * g;

    ushort4 own = make_ushort4(0, 0, 0, 0);   // h(0) = 0 (bf16)
    f32x4 cst = {0.f, 0.f, 0.f, 0.f};
    float hfin[4] = {0.f, 0.f, 0.f, 0.f};

    ushort4 eA = *(const ushort4*)(eb + 0 * 256);
    ushort4 eB = *(const ushort4*)(eb + 1 * 256);

    auto body = [&](int par, ushort4 ef) {
        xch[par][uh][lane] = own;
        asm volatile("s_waitcnt lgkmcnt(0)\ns_barrier" ::: "memory");
        ushort4 oth = xch[par][uh ^ 1][lane];
        ushort4 l0 = uh ? oth : own;   // units 0-15  -> slots 0-3
        ushort4 l1 = uh ? own : oth;   // units 16-31 -> slots 4-7
        bf16x8 Bh = {(short)l0.x, (short)l0.y, (short)l0.z, (short)l0.w,
                     (short)l1.x, (short)l1.y, (short)l1.z, (short)l1.w};
        bf16x8 Be = {(short)ef.x, (short)ef.y, (short)ef.z, (short)ef.w, 0, 0, 0, 0};

        f32x4 gacc[4];
        #pragma unroll
        for (int gi = 0; gi < 4; ++gi) {
            f32x4 a = __builtin_amdgcn_mfma_f32_16x16x32_bf16(Ah[gi], Bh, bias[gi], 0, 0, 0);
            gacc[gi] = __builtin_amdgcn_mfma_f32_16x16x32_bf16(Ae[gi], Be, a, 0, 0, 0);
        }
        unsigned short hb[4];
        #pragma unroll
        for (int r = 0; r < 4; ++r) {
            float f  = fast_sigmoid(gacc[0][r]);
            float i  = fast_sigmoid(gacc[1][r]);
            float ch = fast_tanh(gacc[2][r]);
            float o  = fast_sigmoid(gacc[3][r]);
            float cn = fmaf(f, cst[r], i * ch);
            cst[r] = cn;
            float hv = o * fast_tanh(cn);
            hfin[r] = hv;
            hb[r] = f2bf(hv);
        }
        own = make_ushort4(hb[0], hb[1], hb[2], hb[3]);
    };

    #pragma unroll 1
    for (int t = 0; t < T_; t += 2) {
        body(0, eA);
        if (t + 2 < T_) eA = *(const ushort4*)(eb + (size_t)(t + 2) * 256);
        body(1, eB);
        if (t + 3 < T_) eB = *(const ushort4*)(eb + (size_t)(t + 3) * 256);
    }

    // ---- output projection: p[b] = sum_u h[u,b] * Wout[u]
    float p = 0.f;
    #pragma unroll
    for (int r = 0; r < 4; ++r) p = fmaf(hfin[r], Wout[16 * uh + 4 * g + r], p);
    p += __shfl_xor(p, 16, 64);
    p += __shfl_xor(p, 32, 64);
    if (lane < 16) pred[uh][lane] = p;
    __syncthreads();
    if (tid < 16) out[bt * 16 + tid] = fast_sigmoid(pred[0][tid] + pred[1][tid] + bout[0]);
}

extern "C" void kernel_launch(void* const* d_in, const int* in_sizes, int n_in,
                              void* d_out, int out_size, void* d_ws, size_t ws_size,
                              hipStream_t stream) {
    const float* x    = (const float*)d_in[0];
    const float* Wemb = (const float*)d_in[1];
    const float* bemb = (const float*)d_in[2];
    const float* Wf   = (const float*)d_in[3];
    const float* bfv  = (const float*)d_in[4];
    const float* Wi   = (const float*)d_in[5];
    const float* biv  = (const float*)d_in[6];
    const float* Wc   = (const float*)d_in[7];
    const float* bcv  = (const float*)d_in[8];
    const float* Wo   = (const float*)d_in[9];
    const float* bov  = (const float*)d_in[10];
    const float* Wout = (const float*)d_in[11];
    const float* bout = (const float*)d_in[12];
    float* out = (float*)d_out;
    unsigned short* e_ws = (unsigned short*)d_ws;  // needs 16 MiB

    hipLaunchKernelGGL(embed_kernel, dim3(B_), dim3(256), 0, stream,
                       x, Wemb, bemb, e_ws);
    hipLaunchKernelGGL(lstm_rec, dim3(B_ / 16), dim3(128), 0, stream,
                       Wf, bfv, Wi, biv, Wc, bcv, Wo, bov, Wout, bout, e_ws, out);
}

// Round 3
// 138.596 us; speedup vs baseline: 2.5944x; 1.3528x over previous
//
#include <hip/hip_runtime.h>

#define B_ 2048
#define T_ 256
#define F_ 64
#define EMB_ 16
#define UNITS_ 32
#define NL2E 1.44269504f   // log2(e)

typedef __attribute__((ext_vector_type(8))) short bf16x8;
typedef __attribute__((ext_vector_type(4))) float f32x4;

__device__ __forceinline__ unsigned short f2bf(float f) {  // RNE float->bf16
    unsigned u = __float_as_uint(f);
    return (unsigned short)((u + 0x7FFFu + ((u >> 16) & 1u)) >> 16);
}
__device__ __forceinline__ float fast_sigmoid(float x) {
    return __builtin_amdgcn_rcpf(1.0f + __builtin_amdgcn_exp2f(-NL2E * x));
}

// ---------------- Kernel 1: embedding (coalesced via LDS staging) ------------
// 128 rows per 128-thread block; stage x rows into padded LDS, each thread
// then computes 16 embedding outputs for its row; write bf16 in the
// recurrence's B-fragment order: e_ws[b>>4][t][b&15][emb].
__global__ __launch_bounds__(128) void embed_kernel(
    const float* __restrict__ x, const float* __restrict__ Wemb,
    const float* __restrict__ bemb, unsigned short* __restrict__ e_ws)
{
    __shared__ float sX[128][66];   // pad 64->66: 2-way conflicts only
    __shared__ float sW[F_ * EMB_];
    __shared__ float sB[EMB_];
    const int tid = threadIdx.x;
    for (int i = tid; i < F_ * EMB_; i += 128) sW[i] = Wemb[i];
    if (tid < EMB_) sB[tid] = bemb[tid];

    const size_t r0 = (size_t)blockIdx.x * 128;
    const float4* xg = (const float4*)(x + r0 * F_);
    #pragma unroll
    for (int j = 0; j < 16; ++j) {
        int f4 = tid + 128 * j;
        float4 v = xg[f4];
        int r = f4 >> 4, f = (f4 & 15) * 4;
        *(float2*)&sX[r][f]     = make_float2(v.x, v.y);
        *(float2*)&sX[r][f + 2] = make_float2(v.z, v.w);
    }
    __syncthreads();

    float acc[EMB_];
    #pragma unroll
    for (int m = 0; m < EMB_; ++m) acc[m] = sB[m];
    #pragma unroll
    for (int q = 0; q < 32; ++q) {
        float2 xv = *(const float2*)&sX[tid][2 * q];
        #pragma unroll
        for (int m = 0; m < EMB_; ++m) {
            acc[m] = fmaf(xv.x, sW[(2 * q) * EMB_ + m], acc[m]);
            acc[m] = fmaf(xv.y, sW[(2 * q + 1) * EMB_ + m], acc[m]);
        }
    }
    unsigned wds[8];
    #pragma unroll
    for (int m = 0; m < 8; ++m) {
        unsigned lo = f2bf(fast_sigmoid(acc[2 * m]));
        unsigned hi = f2bf(fast_sigmoid(acc[2 * m + 1]));
        wds[m] = lo | (hi << 16);
    }
    size_t bt = r0 + tid;
    int b = (int)(bt >> 8), t = (int)(bt & 255);
    size_t off = (((size_t)(b >> 4) * T_ + t) * 16 + (b & 15)) * 16;
    uint4* p = (uint4*)(e_ws + off);
    p[0] = make_uint4(wds[0], wds[1], wds[2], wds[3]);
    p[1] = make_uint4(wds[4], wds[5], wds[6], wds[7]);
}

// ---------------- Kernel 2: LSTM recurrence ----------------------------------
// 8 waves/WG, 2 chains (16-row batch tiles) per WG, 64 WGs.
// Wave w owns units [4w,4w+4). M-tile row j -> (gate j&3, unit 4w+(j>>2)), so
// lane (g,m15) gets C rows 4g+r = all 4 gates of cell (unit 4w+g, batch m15).
// A/bias pre-scaled by -log2e (-2log2e for c-gate) so MFMA feeds exp2 directly.
__global__ __launch_bounds__(512) void lstm_rec(
    const float* __restrict__ Wf, const float* __restrict__ bfv,
    const float* __restrict__ Wi, const float* __restrict__ biv,
    const float* __restrict__ Wc, const float* __restrict__ bcv,
    const float* __restrict__ Wo, const float* __restrict__ bov,
    const float* __restrict__ Wout, const float* __restrict__ bout,
    const unsigned short* __restrict__ e_ws, float* __restrict__ out)
{
    __shared__ unsigned short hx[2][2][16][36];  // [chain][buf][batch][unit+pad]
    __shared__ float pred[2][8][16];

    const int tid = threadIdx.x;
    const int w = tid >> 6;
    const int lane = tid & 63;
    const int g = lane >> 4, m15 = lane & 15;

    // ---- A fragments: row m15 -> gate m15&3, unit 4w + (m15>>2) ----
    const int gate = m15 & 3;
    const int au = 4 * w + (m15 >> 2);
    const float* Wsel = (gate == 0) ? Wf : (gate == 1) ? Wi : (gate == 2) ? Wc : Wo;
    const float ascale = (gate == 2) ? (-2.0f * NL2E) : (-NL2E);
    bf16x8 Ah, Ae;
    #pragma unroll
    for (int j = 0; j < 4; ++j) {
        Ah[j]     = (short)f2bf(ascale * Wsel[(4 * g + j)      * UNITS_ + au]);
        Ah[j + 4] = (short)f2bf(ascale * Wsel[(16 + 4 * g + j) * UNITS_ + au]);
        Ae[j]     = (short)f2bf(ascale * Wsel[(32 + 4 * g + j) * UNITS_ + au]);
        Ae[j + 4] = 0;
    }
    const int cu = 4 * w + g;   // this lane's cell unit (C rows = 4 gates of it)
    f32x4 bias;
    bias[0] = -NL2E * bfv[cu];
    bias[1] = -NL2E * biv[cu];
    bias[2] = -2.0f * NL2E * bcv[cu];
    bias[3] = -NL2E * bov[cu];

    const int btA = blockIdx.x * 2, btB = btA + 1;
    const unsigned short* ebA = e_ws + (size_t)btA * T_ * 256 + m15 * 16 + 4 * g;
    const unsigned short* ebB = e_ws + (size_t)btB * T_ * 256 + m15 * 16 + 4 * g;

    float cA = 0.f, cB = 0.f, hfA = 0.f, hfB = 0.f;
    bf16x8 BhA, BhB;
    #pragma unroll
    for (int j = 0; j < 8; ++j) { BhA[j] = 0; BhB[j] = 0; }

    ushort4 eA[4], eB[4];
    #pragma unroll
    for (int s = 0; s < 4; ++s) {
        eA[s] = *(const ushort4*)(ebA + (size_t)s * 256);
        eB[s] = *(const ushort4*)(ebB + (size_t)s * 256);
    }

    // gates (f,i,cbar,o) already scaled: acc = -L2E*g (c: -2L2E*g).
    auto cell = [&](const f32x4& acc, float& cst, float& hf) -> unsigned short {
        float Ef = __builtin_amdgcn_exp2f(acc[0]);           // e^-gf
        float Ei = __builtin_amdgcn_exp2f(acc[1]);           // e^-gi
        float Ec = __builtin_amdgcn_exp2f(acc[2]);           // e^-2gc
        float Eo = __builtin_amdgcn_exp2f(acc[3]);           // e^-go
        float Pf = 1.f + Ef, Pi = 1.f + Ei, Pc = 1.f + Ec, Po = 1.f + Eo;
        float Mc = 1.f - Ec;
        float t1 = Pi * Pc;
        float num = fmaf(cst, t1, Pf * Mc);                  // c*PiPc + Pf*(1-Ec)
        float den = Pf * t1;
        float cn = num * __builtin_amdgcn_rcpf(den);
        cst = cn;
        float Eh = __builtin_amdgcn_exp2f(cn * (-2.0f * NL2E));
        float Mh = 1.f - Eh;
        float d2 = (1.f + Eh) * Po;
        hf = Mh * __builtin_amdgcn_rcpf(d2);                 // tanh(cn)*sigmoid(go)
        return f2bf(hf);
    };

    auto step = [&](int buf, const ushort4& evA, const ushort4& evB) {
        bf16x8 BeA = {(short)evA.x, (short)evA.y, (short)evA.z, (short)evA.w, 0, 0, 0, 0};
        bf16x8 BeB = {(short)evB.x, (short)evB.y, (short)evB.z, (short)evB.w, 0, 0, 0, 0};
        f32x4 aA = __builtin_amdgcn_mfma_f32_16x16x32_bf16(Ah, BhA, bias, 0, 0, 0);
        f32x4 aB = __builtin_amdgcn_mfma_f32_16x16x32_bf16(Ah, BhB, bias, 0, 0, 0);
        aA = __builtin_amdgcn_mfma_f32_16x16x32_bf16(Ae, BeA, aA, 0, 0, 0);
        aB = __builtin_amdgcn_mfma_f32_16x16x32_bf16(Ae, BeB, aB, 0, 0, 0);
        hx[0][buf][m15][cu] = cell(aA, cA, hfA);
        hx[1][buf][m15][cu] = cell(aB, cB, hfB);
        __syncthreads();
        const unsigned short* pa = &hx[0][buf][m15][0];
        const unsigned short* pb = &hx[1][buf][m15][0];
        ushort4 a0 = *(const ushort4*)(pa + 4 * g);
        ushort4 a1 = *(const ushort4*)(pa + 16 + 4 * g);
        ushort4 b0 = *(const ushort4*)(pb + 4 * g);
        ushort4 b1 = *(const ushort4*)(pb + 16 + 4 * g);
        BhA = bf16x8{(short)a0.x, (short)a0.y, (short)a0.z, (short)a0.w,
                     (short)a1.x, (short)a1.y, (short)a1.z, (short)a1.w};
        BhB = bf16x8{(short)b0.x, (short)b0.y, (short)b0.z, (short)b0.w,
                     (short)b1.x, (short)b1.y, (short)b1.z, (short)b1.w};
    };

    #pragma unroll 1
    for (int t = 0; t < T_; t += 4) {
        #pragma unroll
        for (int s = 0; s < 4; ++s) {
            ushort4 evA = eA[s], evB = eB[s];
            int tn = t + s + 4;
            int tl = (tn < T_) ? tn : (T_ - 1);
            eA[s] = *(const ushort4*)(ebA + (size_t)tl * 256);   // prefetch
            eB[s] = *(const ushort4*)(ebB + (size_t)tl * 256);
            step((t + s) & 1, evA, evB);
        }
    }

    // ---- output projection ----
    float pA = hfA * Wout[cu];
    float pB = hfB * Wout[cu];
    pA += __shfl_xor(pA, 16, 64); pA += __shfl_xor(pA, 32, 64);
    pB += __shfl_xor(pB, 16, 64); pB += __shfl_xor(pB, 32, 64);
    if (lane < 16) { pred[0][w][m15] = pA; pred[1][w][m15] = pB; }
    __syncthreads();
    if (tid < 32) {
        int c = tid >> 4, m = tid & 15;
        float sum = bout[0];
        #pragma unroll
        for (int ww = 0; ww < 8; ++ww) sum += pred[c][ww][m];
        out[(btA + c) * 16 + m] = fast_sigmoid(sum);
    }
}

extern "C" void kernel_launch(void* const* d_in, const int* in_sizes, int n_in,
                              void* d_out, int out_size, void* d_ws, size_t ws_size,
                              hipStream_t stream) {
    const float* x    = (const float*)d_in[0];
    const float* Wemb = (const float*)d_in[1];
    const float* bemb = (const float*)d_in[2];
    const float* Wf   = (const float*)d_in[3];
    const float* bfv  = (const float*)d_in[4];
    const float* Wi   = (const float*)d_in[5];
    const float* biv  = (const float*)d_in[6];
    const float* Wc   = (const float*)d_in[7];
    const float* bcv  = (const float*)d_in[8];
    const float* Wo   = (const float*)d_in[9];
    const float* bov  = (const float*)d_in[10];
    const float* Wout = (const float*)d_in[11];
    const float* bout = (const float*)d_in[12];
    float* out = (float*)d_out;
    unsigned short* e_ws = (unsigned short*)d_ws;  // 16 MiB

    hipLaunchKernelGGL(embed_kernel, dim3((B_ * T_) / 128), dim3(128), 0, stream,
                       x, Wemb, bemb, e_ws);
    hipLaunchKernelGGL(lstm_rec, dim3(B_ / 32), dim3(512), 0, stream,
                       Wf, bfv, Wi, biv, Wc, bcv, Wo, bov, Wout, bout, e_ws, out);
}

// Round 4
// 126.543 us; speedup vs baseline: 2.8415x; 1.0952x over previous
//
#include <hip/hip_runtime.h>

#define B_ 2048
#define T_ 256
#define F_ 64
#define EMB_ 16
#define UNITS_ 32
#define L2E 1.44269504f

typedef __attribute__((ext_vector_type(8))) short bf16x8;
typedef __attribute__((ext_vector_type(4))) float f32x4;

__device__ __forceinline__ unsigned short f2bf(float f) {  // RNE float->bf16
    unsigned u = __float_as_uint(f);
    return (unsigned short)((u + 0x7FFFu + ((u >> 16) & 1u)) >> 16);
}
__device__ __forceinline__ float fast_sigmoid(float x) {
    return __builtin_amdgcn_rcpf(1.0f + __builtin_amdgcn_exp2f(-L2E * x));
}

// ---------------- Kernel 1: embedding via MFMA -------------------------------
// e[16emb x 16batch] = sigmoid(Wemb^T x^T + b) per t. A = static bf16 Wemb
// fragments; B = x staged coalesced into LDS (bf16). C lane (g,n) reg r =
// e[4g+r][batch n] -> stored at e_ws[tile][t][lane] (8B), which is exactly the
// Be fragment the recurrence lane (g,m15) consumes. Gauge (verified family):
// slot j <-> k = 4g+j (j<4), 16+4g+(j-4) (j>=4).
__global__ __launch_bounds__(64) void embed_mfma(
    const float* __restrict__ x, const float* __restrict__ Wemb,
    const float* __restrict__ bemb, unsigned int* __restrict__ e_ws)
{
    __shared__ unsigned short slab[2][16][72];   // bf16 x rows, padded

    const int lane = threadIdx.x;
    const int g = lane >> 4, c = lane & 15;
    const int tile = blockIdx.x >> 5;        // 128 batch tiles
    const int t0 = (blockIdx.x & 31) * 8;    // 32 t-chunks of 8

    // static A fragments (K=64 -> 2 MFMAs)
    bf16x8 A1, A2;
    #pragma unroll
    for (int j = 0; j < 4; ++j) {
        A1[j]     = (short)f2bf(Wemb[(4 * g + j) * EMB_ + c]);
        A1[j + 4] = (short)f2bf(Wemb[(16 + 4 * g + j) * EMB_ + c]);
        A2[j]     = (short)f2bf(Wemb[(32 + 4 * g + j) * EMB_ + c]);
        A2[j + 4] = (short)f2bf(Wemb[(48 + 4 * g + j) * EMB_ + c]);
    }
    f32x4 bc;
    #pragma unroll
    for (int r = 0; r < 4; ++r) bc[r] = bemb[4 * g + r];

    const int sr = lane >> 2, sc = lane & 3;             // staging: row, quarter
    const float* xs = x + (size_t)(tile * 16 + sr) * T_ * F_ + sc * 16;

    float4 rld[4], nld[4];
    {
        const float4* p = (const float4*)(xs + (size_t)t0 * F_);
        rld[0] = p[0]; rld[1] = p[1]; rld[2] = p[2]; rld[3] = p[3];
    }

    #pragma unroll
    for (int i = 0; i < 9; ++i) {
        if (i < 7) {
            const float4* p = (const float4*)(xs + (size_t)(t0 + i + 1) * F_);
            nld[0] = p[0]; nld[1] = p[1]; nld[2] = p[2]; nld[3] = p[3];
        }
        if (i < 8) {   // pack r -> slab[i&1]
            const float* f = (const float*)rld;
            unsigned u[8];
            #pragma unroll
            for (int k = 0; k < 8; ++k)
                u[k] = (unsigned)f2bf(f[2 * k]) | ((unsigned)f2bf(f[2 * k + 1]) << 16);
            uint4* d = (uint4*)&slab[i & 1][sr][sc * 16];
            d[0] = make_uint4(u[0], u[1], u[2], u[3]);
            d[1] = make_uint4(u[4], u[5], u[6], u[7]);
        }
        if (i > 0) {   // compute t = t0+i-1 from slab[(i-1)&1]
            const unsigned short* row = &slab[(i - 1) & 1][c][0];
            ushort4 l1 = *(const ushort4*)(row + 4 * g);
            ushort4 h1 = *(const ushort4*)(row + 16 + 4 * g);
            ushort4 l2 = *(const ushort4*)(row + 32 + 4 * g);
            ushort4 h2 = *(const ushort4*)(row + 48 + 4 * g);
            bf16x8 B1 = {(short)l1.x, (short)l1.y, (short)l1.z, (short)l1.w,
                         (short)h1.x, (short)h1.y, (short)h1.z, (short)h1.w};
            bf16x8 B2 = {(short)l2.x, (short)l2.y, (short)l2.z, (short)l2.w,
                         (short)h2.x, (short)h2.y, (short)h2.z, (short)h2.w};
            f32x4 acc = __builtin_amdgcn_mfma_f32_16x16x32_bf16(A1, B1, bc, 0, 0, 0);
            acc = __builtin_amdgcn_mfma_f32_16x16x32_bf16(A2, B2, acc, 0, 0, 0);
            unsigned u0 = (unsigned)f2bf(fast_sigmoid(acc[0])) |
                          ((unsigned)f2bf(fast_sigmoid(acc[1])) << 16);
            unsigned u1 = (unsigned)f2bf(fast_sigmoid(acc[2])) |
                          ((unsigned)f2bf(fast_sigmoid(acc[3])) << 16);
            size_t idx = (((size_t)tile * T_ + (t0 + i - 1)) * 64 + lane) * 2;
            *(uint2*)(e_ws + idx) = make_uint2(u0, u1);
        }
        #pragma unroll
        for (int k = 0; k < 4; ++k) rld[k] = nld[k];
    }
}

// ---------------- Kernel 2: LSTM recurrence ----------------------------------
// 128 WGs x 4 waves (1 wave/SIMD). Wave w owns units [8w,8w+8) as 2 M-tiles:
// tile tau covers units 8w+2k+tau (k=0..3); row m -> (gate m&3, k=m>>2).
// Lane (g,m15): C rows 4g+r = 4 gates of cell (unit 8w+2g+tau, batch m15);
// its two cells are ADJACENT units -> one packed b32 h-write. Bh read: two
// ds_read_b64 from hx[m15][4g..] / [16+4g..] (verified gauge). A/bias
// pre-scaled by -log2e (-2log2e for c-gate) so MFMA output feeds exp2.
__global__ __launch_bounds__(256) void lstm_rec(
    const float* __restrict__ Wf, const float* __restrict__ bfv,
    const float* __restrict__ Wi, const float* __restrict__ biv,
    const float* __restrict__ Wc, const float* __restrict__ bcv,
    const float* __restrict__ Wo, const float* __restrict__ bov,
    const float* __restrict__ Wout, const float* __restrict__ bout,
    const unsigned int* __restrict__ e_ws, float* __restrict__ out)
{
    __shared__ unsigned short hx[2][16][40];   // [buf][batch][unit], padded
    __shared__ float pred[4][16];

    const int tid = threadIdx.x;
    const int w = tid >> 6;
    const int lane = tid & 63;
    const int g = lane >> 4, m15 = lane & 15;
    const int bt = blockIdx.x;

    const int gate = m15 & 3;
    const float* Wsel = (gate == 0) ? Wf : (gate == 1) ? Wi : (gate == 2) ? Wc : Wo;
    const float ascale = (gate == 2) ? (-2.0f * L2E) : (-L2E);
    const int uAb = 8 * w + 2 * (m15 >> 2);

    bf16x8 Ah[2], Ae[2];
    #pragma unroll
    for (int tau = 0; tau < 2; ++tau) {
        const int uA = uAb + tau;
        #pragma unroll
        for (int j = 0; j < 4; ++j) {
            Ah[tau][j]     = (short)f2bf(ascale * Wsel[(4 * g + j) * UNITS_ + uA]);
            Ah[tau][j + 4] = (short)f2bf(ascale * Wsel[(16 + 4 * g + j) * UNITS_ + uA]);
            Ae[tau][j]     = (short)f2bf(ascale * Wsel[(32 + 4 * g + j) * UNITS_ + uA]);
            Ae[tau][j + 4] = 0;
        }
    }
    f32x4 bias[2];
    #pragma unroll
    for (int tau = 0; tau < 2; ++tau) {
        const int u = 8 * w + 2 * g + tau;
        bias[tau][0] = -L2E * bfv[u];
        bias[tau][1] = -L2E * biv[u];
        bias[tau][2] = -2.0f * L2E * bcv[u];
        bias[tau][3] = -L2E * bov[u];
    }

    const uint2* ep = (const uint2*)e_ws + (size_t)bt * T_ * 64 + lane;
    uint2 ering[4];
    #pragma unroll
    for (int s = 0; s < 4; ++s) ering[s] = ep[(size_t)s * 64];

    for (int i = tid; i < 2 * 16 * 40 / 2; i += 256) ((unsigned*)hx)[i] = 0;
    __syncthreads();

    float c0 = 0.f, c1 = 0.f, hf0 = 0.f, hf1 = 0.f;

    auto cell = [&](const f32x4& acc, float& cst, float& hf) -> unsigned {
        float Ef = __builtin_amdgcn_exp2f(acc[0]);
        float Ei = __builtin_amdgcn_exp2f(acc[1]);
        float Ec = __builtin_amdgcn_exp2f(acc[2]);
        float Eo = __builtin_amdgcn_exp2f(acc[3]);
        float Pf = 1.f + Ef, Pi = 1.f + Ei, Pc = 1.f + Ec, Po = 1.f + Eo;
        float Mc = 1.f - Ec;
        float t1 = Pi * Pc;
        float num = fmaf(cst, t1, Pf * Mc);
        float den = Pf * t1;
        float cn = num * __builtin_amdgcn_rcpf(den);
        cst = cn;
        float Eh = __builtin_amdgcn_exp2f(cn * (-2.0f * L2E));
        float Mh = 1.f - Eh;
        float d2 = (1.f + Eh) * Po;
        hf = Mh * __builtin_amdgcn_rcpf(d2);
        return (unsigned)f2bf(hf);
    };

    #pragma unroll 1
    for (int t = 0; t < T_; ++t) {
        const unsigned short* hrow = &hx[t & 1][m15][0];
        ushort4 hlo = *(const ushort4*)(hrow + 4 * g);
        ushort4 hhi = *(const ushort4*)(hrow + 16 + 4 * g);
        bf16x8 Bh = {(short)hlo.x, (short)hlo.y, (short)hlo.z, (short)hlo.w,
                     (short)hhi.x, (short)hhi.y, (short)hhi.z, (short)hhi.w};
        uint2 ev = ering[t & 3];
        int tn = (t + 4 < T_) ? t + 4 : T_ - 1;
        ering[t & 3] = ep[(size_t)tn * 64];
        bf16x8 Be = {(short)(ev.x & 0xffff), (short)(ev.x >> 16),
                     (short)(ev.y & 0xffff), (short)(ev.y >> 16), 0, 0, 0, 0};

        f32x4 a0 = __builtin_amdgcn_mfma_f32_16x16x32_bf16(Ah[0], Bh, bias[0], 0, 0, 0);
        f32x4 a1 = __builtin_amdgcn_mfma_f32_16x16x32_bf16(Ah[1], Bh, bias[1], 0, 0, 0);
        a0 = __builtin_amdgcn_mfma_f32_16x16x32_bf16(Ae[0], Be, a0, 0, 0, 0);
        a1 = __builtin_amdgcn_mfma_f32_16x16x32_bf16(Ae[1], Be, a1, 0, 0, 0);

        unsigned hb0 = cell(a0, c0, hf0);
        unsigned hb1 = cell(a1, c1, hf1);
        *(unsigned*)&hx[(t + 1) & 1][m15][8 * w + 2 * g] = hb0 | (hb1 << 16);
        __syncthreads();
    }

    float p = hf0 * Wout[8 * w + 2 * g] + hf1 * Wout[8 * w + 2 * g + 1];
    p += __shfl_xor(p, 16, 64);
    p += __shfl_xor(p, 32, 64);
    if (lane < 16) pred[w][lane] = p;
    __syncthreads();
    if (tid < 16)
        out[bt * 16 + tid] = fast_sigmoid(pred[0][tid] + pred[1][tid] +
                                          pred[2][tid] + pred[3][tid] + bout[0]);
}

extern "C" void kernel_launch(void* const* d_in, const int* in_sizes, int n_in,
                              void* d_out, int out_size, void* d_ws, size_t ws_size,
                              hipStream_t stream) {
    const float* x    = (const float*)d_in[0];
    const float* Wemb = (const float*)d_in[1];
    const float* bemb = (const float*)d_in[2];
    const float* Wf   = (const float*)d_in[3];
    const float* bfv  = (const float*)d_in[4];
    const float* Wi   = (const float*)d_in[5];
    const float* biv  = (const float*)d_in[6];
    const float* Wc   = (const float*)d_in[7];
    const float* bcv  = (const float*)d_in[8];
    const float* Wo   = (const float*)d_in[9];
    const float* bov  = (const float*)d_in[10];
    const float* Wout = (const float*)d_in[11];
    const float* bout = (const float*)d_in[12];
    float* out = (float*)d_out;
    unsigned int* e_ws = (unsigned int*)d_ws;   // 16 MiB fragment-layout e

    hipLaunchKernelGGL(embed_mfma, dim3(128 * 32), dim3(64), 0, stream,
                       x, Wemb, bemb, e_ws);
    hipLaunchKernelGGL(lstm_rec, dim3(B_ / 16), dim3(256), 0, stream,
                       Wf, bfv, Wi, biv, Wc, bcv, Wo, bov, Wout, bout,
                       (const unsigned int*)e_ws, out);
}

// Round 5
// 88.373 us; speedup vs baseline: 4.0688x; 1.4319x over previous
//
#include <hip/hip_runtime.h>

#define B_ 2048
#define T_ 256
#define F_ 64
#define EMB_ 16
#define UNITS_ 32
#define L2E 1.44269504f

typedef __attribute__((ext_vector_type(8))) short bf16x8;
typedef __attribute__((ext_vector_type(4))) float f32x4;

__device__ __forceinline__ unsigned short f2bf(float f) {  // RNE float->bf16
    unsigned u = __float_as_uint(f);
    return (unsigned short)((u + 0x7FFFu + ((u >> 16) & 1u)) >> 16);
}
__device__ __forceinline__ float fast_sigmoid(float x) {
    return __builtin_amdgcn_rcpf(1.0f + __builtin_amdgcn_exp2f(-L2E * x));
}

// ---------------- Kernel 1: embedding via MFMA (unchanged from r4) ----------
__global__ __launch_bounds__(64) void embed_mfma(
    const float* __restrict__ x, const float* __restrict__ Wemb,
    const float* __restrict__ bemb, unsigned int* __restrict__ e_ws)
{
    __shared__ unsigned short slab[2][16][72];

    const int lane = threadIdx.x;
    const int g = lane >> 4, c = lane & 15;
    const int tile = blockIdx.x >> 5;
    const int t0 = (blockIdx.x & 31) * 8;

    bf16x8 A1, A2;
    #pragma unroll
    for (int j = 0; j < 4; ++j) {
        A1[j]     = (short)f2bf(Wemb[(4 * g + j) * EMB_ + c]);
        A1[j + 4] = (short)f2bf(Wemb[(16 + 4 * g + j) * EMB_ + c]);
        A2[j]     = (short)f2bf(Wemb[(32 + 4 * g + j) * EMB_ + c]);
        A2[j + 4] = (short)f2bf(Wemb[(48 + 4 * g + j) * EMB_ + c]);
    }
    f32x4 bc;
    #pragma unroll
    for (int r = 0; r < 4; ++r) bc[r] = bemb[4 * g + r];

    const int sr = lane >> 2, sc = lane & 3;
    const float* xs = x + (size_t)(tile * 16 + sr) * T_ * F_ + sc * 16;

    float4 rld[4], nld[4];
    {
        const float4* p = (const float4*)(xs + (size_t)t0 * F_);
        rld[0] = p[0]; rld[1] = p[1]; rld[2] = p[2]; rld[3] = p[3];
    }

    #pragma unroll
    for (int i = 0; i < 9; ++i) {
        if (i < 7) {
            const float4* p = (const float4*)(xs + (size_t)(t0 + i + 1) * F_);
            nld[0] = p[0]; nld[1] = p[1]; nld[2] = p[2]; nld[3] = p[3];
        }
        if (i < 8) {
            const float* f = (const float*)rld;
            unsigned u[8];
            #pragma unroll
            for (int k = 0; k < 8; ++k)
                u[k] = (unsigned)f2bf(f[2 * k]) | ((unsigned)f2bf(f[2 * k + 1]) << 16);
            uint4* d = (uint4*)&slab[i & 1][sr][sc * 16];
            d[0] = make_uint4(u[0], u[1], u[2], u[3]);
            d[1] = make_uint4(u[4], u[5], u[6], u[7]);
        }
        if (i > 0) {
            const unsigned short* row = &slab[(i - 1) & 1][c][0];
            ushort4 l1 = *(const ushort4*)(row + 4 * g);
            ushort4 h1 = *(const ushort4*)(row + 16 + 4 * g);
            ushort4 l2 = *(const ushort4*)(row + 32 + 4 * g);
            ushort4 h2 = *(const ushort4*)(row + 48 + 4 * g);
            bf16x8 B1 = {(short)l1.x, (short)l1.y, (short)l1.z, (short)l1.w,
                         (short)h1.x, (short)h1.y, (short)h1.z, (short)h1.w};
            bf16x8 B2 = {(short)l2.x, (short)l2.y, (short)l2.z, (short)l2.w,
                         (short)h2.x, (short)h2.y, (short)h2.z, (short)h2.w};
            f32x4 acc = __builtin_amdgcn_mfma_f32_16x16x32_bf16(A1, B1, bc, 0, 0, 0);
            acc = __builtin_amdgcn_mfma_f32_16x16x32_bf16(A2, B2, acc, 0, 0, 0);
            unsigned u0 = (unsigned)f2bf(fast_sigmoid(acc[0])) |
                          ((unsigned)f2bf(fast_sigmoid(acc[1])) << 16);
            unsigned u1 = (unsigned)f2bf(fast_sigmoid(acc[2])) |
                          ((unsigned)f2bf(fast_sigmoid(acc[3])) << 16);
            size_t idx = (((size_t)tile * T_ + (t0 + i - 1)) * 64 + lane) * 2;
            *(uint2*)(e_ws + idx) = make_uint2(u0, u1);
        }
        #pragma unroll
        for (int k = 0; k < 4; ++k) rld[k] = nld[k];
    }
}

// ---------------- Kernel 2: LSTM recurrence ----------------------------------
// 128 WGs x 4 waves (1 wave/SIMD). Same decomposition as r4, plus:
//  - raw lgkm-only barrier (e-prefetch loads stay in flight across steps)
//  - Fe = mfma(Ae, Be(t+1), bias) precomputed one step ahead -> the h-critical
//    path has exactly ONE dependent MFMA: a = mfma(Ah, Bh, Fe)
//  - hx stride 36 (conflict-free), packed h-write via v_cvt_pk_bf16_f32
__global__ __launch_bounds__(256) void lstm_rec(
    const float* __restrict__ Wf, const float* __restrict__ bfv,
    const float* __restrict__ Wi, const float* __restrict__ biv,
    const float* __restrict__ Wc, const float* __restrict__ bcv,
    const float* __restrict__ Wo, const float* __restrict__ bov,
    const float* __restrict__ Wout, const float* __restrict__ bout,
    const unsigned int* __restrict__ e_ws, float* __restrict__ out)
{
    __shared__ unsigned short hx[2][16][36];   // [buf][batch][unit], stride 72B
    __shared__ float pred[4][16];

    const int tid = threadIdx.x;
    const int w = tid >> 6;
    const int lane = tid & 63;
    const int g = lane >> 4, m15 = lane & 15;
    const int bt = blockIdx.x;

    const int gate = m15 & 3;
    const float* Wsel = (gate == 0) ? Wf : (gate == 1) ? Wi : (gate == 2) ? Wc : Wo;
    const float ascale = (gate == 2) ? (-2.0f * L2E) : (-L2E);
    const int uAb = 8 * w + 2 * (m15 >> 2);

    bf16x8 Ah[2], Ae[2];
    #pragma unroll
    for (int tau = 0; tau < 2; ++tau) {
        const int uA = uAb + tau;
        #pragma unroll
        for (int j = 0; j < 4; ++j) {
            Ah[tau][j]     = (short)f2bf(ascale * Wsel[(4 * g + j) * UNITS_ + uA]);
            Ah[tau][j + 4] = (short)f2bf(ascale * Wsel[(16 + 4 * g + j) * UNITS_ + uA]);
            Ae[tau][j]     = (short)f2bf(ascale * Wsel[(32 + 4 * g + j) * UNITS_ + uA]);
            Ae[tau][j + 4] = 0;
        }
    }
    f32x4 bias[2];
    #pragma unroll
    for (int tau = 0; tau < 2; ++tau) {
        const int u = 8 * w + 2 * g + tau;
        bias[tau][0] = -L2E * bfv[u];
        bias[tau][1] = -L2E * biv[u];
        bias[tau][2] = -2.0f * L2E * bcv[u];
        bias[tau][3] = -L2E * bov[u];
    }

    const uint2* ep = (const uint2*)e_ws + (size_t)bt * T_ * 64 + lane;
    uint2 ering[4];
    #pragma unroll
    for (int s = 0; s < 4; ++s) ering[s] = ep[(size_t)s * 64];

    for (int i = tid; i < 2 * 16 * 36 / 2; i += 256) ((unsigned*)hx)[i] = 0;
    __syncthreads();

    float c0 = 0.f, c1 = 0.f, hf0 = 0.f, hf1 = 0.f;

    auto cell = [&](const f32x4& acc, float& cst, float& hf) {
        float Ef = __builtin_amdgcn_exp2f(acc[0]);
        float Ei = __builtin_amdgcn_exp2f(acc[1]);
        float Ec = __builtin_amdgcn_exp2f(acc[2]);
        float Eo = __builtin_amdgcn_exp2f(acc[3]);
        float Pf = 1.f + Ef, Pi = 1.f + Ei, Pc = 1.f + Ec, Po = 1.f + Eo;
        float Mc = 1.f - Ec;
        float t1 = Pi * Pc;
        float num = fmaf(cst, t1, Pf * Mc);
        float den = Pf * t1;
        float cn = num * __builtin_amdgcn_rcpf(den);
        cst = cn;
        float Eh = __builtin_amdgcn_exp2f(cn * (-2.0f * L2E));
        float Mh = 1.f - Eh;
        float d2 = (1.f + Eh) * Po;
        hf = Mh * __builtin_amdgcn_rcpf(d2);
    };

    // Fe for step 0 (bias + We*e(0)), h-independent
    f32x4 Fe0, Fe1;
    {
        uint2 ev = ering[0];
        bf16x8 Be = {(short)(ev.x & 0xffff), (short)(ev.x >> 16),
                     (short)(ev.y & 0xffff), (short)(ev.y >> 16), 0, 0, 0, 0};
        Fe0 = __builtin_amdgcn_mfma_f32_16x16x32_bf16(Ae[0], Be, bias[0], 0, 0, 0);
        Fe1 = __builtin_amdgcn_mfma_f32_16x16x32_bf16(Ae[1], Be, bias[1], 0, 0, 0);
    }

    #pragma unroll 1
    for (int t = 0; t < T_; t += 4) {
        #pragma unroll
        for (int s = 0; s < 4; ++s) {
            const int u = t + s;
            // h-dependent path: read h -> ONE mfma -> cell
            const unsigned short* hrow = &hx[u & 1][m15][0];
            ushort4 hlo = *(const ushort4*)(hrow + 4 * g);
            ushort4 hhi = *(const ushort4*)(hrow + 16 + 4 * g);
            bf16x8 Bh = {(short)hlo.x, (short)hlo.y, (short)hlo.z, (short)hlo.w,
                         (short)hhi.x, (short)hhi.y, (short)hhi.z, (short)hhi.w};
            f32x4 a0 = __builtin_amdgcn_mfma_f32_16x16x32_bf16(Ah[0], Bh, Fe0, 0, 0, 0);
            f32x4 a1 = __builtin_amdgcn_mfma_f32_16x16x32_bf16(Ah[1], Bh, Fe1, 0, 0, 0);

            // refill ring slot s with e(u+4); consume slot (s+1)&3 for Fe(u+1)
            int tn = (u + 4 < T_) ? u + 4 : T_ - 1;
            uint2 ev = ering[(s + 1) & 3];
            ering[s] = ep[(size_t)tn * 64];
            bf16x8 Be = {(short)(ev.x & 0xffff), (short)(ev.x >> 16),
                         (short)(ev.y & 0xffff), (short)(ev.y >> 16), 0, 0, 0, 0};
            Fe0 = __builtin_amdgcn_mfma_f32_16x16x32_bf16(Ae[0], Be, bias[0], 0, 0, 0);
            Fe1 = __builtin_amdgcn_mfma_f32_16x16x32_bf16(Ae[1], Be, bias[1], 0, 0, 0);

            cell(a0, c0, hf0);
            cell(a1, c1, hf1);
            unsigned pk;
            asm("v_cvt_pk_bf16_f32 %0, %1, %2" : "=v"(pk) : "v"(hf0), "v"(hf1));
            *(unsigned*)&hx[(u + 1) & 1][m15][8 * w + 2 * g] = pk;

            // lgkm-only barrier: e-prefetch (vmcnt) stays in flight
            asm volatile("s_waitcnt lgkmcnt(0)\n\ts_barrier" ::: "memory");
        }
    }

    float p = hf0 * Wout[8 * w + 2 * g] + hf1 * Wout[8 * w + 2 * g + 1];
    p += __shfl_xor(p, 16, 64);
    p += __shfl_xor(p, 32, 64);
    if (lane < 16) pred[w][lane] = p;
    __syncthreads();
    if (tid < 16)
        out[bt * 16 + tid] = fast_sigmoid(pred[0][tid] + pred[1][tid] +
                                          pred[2][tid] + pred[3][tid] + bout[0]);
}

extern "C" void kernel_launch(void* const* d_in, const int* in_sizes, int n_in,
                              void* d_out, int out_size, void* d_ws, size_t ws_size,
                              hipStream_t stream) {
    const float* x    = (const float*)d_in[0];
    const float* Wemb = (const float*)d_in[1];
    const float* bemb = (const float*)d_in[2];
    const float* Wf   = (const float*)d_in[3];
    const float* bfv  = (const float*)d_in[4];
    const float* Wi   = (const float*)d_in[5];
    const float* biv  = (const float*)d_in[6];
    const float* Wc   = (const float*)d_in[7];
    const float* bcv  = (const float*)d_in[8];
    const float* Wo   = (const float*)d_in[9];
    const float* bov  = (const float*)d_in[10];
    const float* Wout = (const float*)d_in[11];
    const float* bout = (const float*)d_in[12];
    float* out = (float*)d_out;
    unsigned int* e_ws = (unsigned int*)d_ws;   // 16 MiB fragment-layout e

    hipLaunchKernelGGL(embed_mfma, dim3(128 * 32), dim3(64), 0, stream,
                       x, Wemb, bemb, e_ws);
    hipLaunchKernelGGL(lstm_rec, dim3(B_ / 16), dim3(256), 0, stream,
                       Wf, bfv, Wi, biv, Wc, bcv, Wo, bov, Wout, bout,
                       (const unsigned int*)e_ws, out);
}